// Round 17
// baseline (4252.440 us; speedup 1.0000x reference)
//
#include <hip/hip_runtime.h>
#include <hip/hip_cooperative_groups.h>
#include <cstdint>

namespace cg = cooperative_groups;

// Problem constants
#define B_   64
#define Z_   512
#define U_   2048
#define T_   32
#define DIN_ 90
#define G4_  8192      // 4*U
#define STLD 12288     // setup GEMM output row stride: h at +l*4096, c at +l*4096+2048

using bf16x8 = __attribute__((ext_vector_type(8))) short;   // 8 bf16 = 4 VGPRs
using f32x4  = __attribute__((ext_vector_type(4))) float;

#define MFMA(a, b, c) __builtin_amdgcn_mfma_f32_16x16x32_bf16((a), (b), (c), 0, 0, 0)

__device__ __forceinline__ unsigned short f2bf(float f) {
    unsigned int u = __float_as_uint(f);
    unsigned int r = (u + 0x7FFFu + ((u >> 16) & 1u)) >> 16;   // RNE
    return (unsigned short)r;
}
__device__ __forceinline__ float sigf(float x) { return 1.f / (1.f + expf(-x)); }

// async global->LDS, 16 B per lane; LDS dest is wave-uniform base + lane*16
__device__ __forceinline__ void gld16(const void* g, void* l) {
    __builtin_amdgcn_global_load_lds(
        (const __attribute__((address_space(1))) unsigned int*)g,
        (__attribute__((address_space(3))) unsigned int*)l, 16, 0, 0);
}

// ======== staged K=2048 GEMM core as macros (LDS at kernel scope; passing ========
// ======== __shared__ pointers through fn params ICEs clang — r11 lesson)  ========
// 512 threads = 8 waves. Block tile: 64 rows x 32 packed cols. Wave (rq=wv&3,
// ch=wv>>2) does 16x16. KT=128; stage = A 16KB | W 8KB = 24KB; SIX stages =
// 144KB (1 block/CU by design); prefetch distance 5 tiles. r16 post-mortem:
// depth-2 covered ~200ns of ~900ns load latency -> tau=450ns/tile; depth-5
// covers ~latency -> tau ~ compute rate. Wait schedule: vmcnt(12), tail 9/6/3/0.
// T2 XOR swizzle via pre-swizzled global source. sg aliases stage buffer 2.
// Requires in scope: stg, t, wv, l, rq, ch, lr; epilogues also need `til`.
#define GEMM_PROLOG()                                                        \
    size_t ag0, ag1, wg0; unsigned al0, al1, wl0;                            \
    {                                                                        \
        int kb0 = (l & 15) << 4;                                             \
        int r0 = wv * 4 + (l >> 4);                   /* rows 0..31 */       \
        int sw0 = kb0 ^ ((r0 & 7) << 4);                                     \
        ag0 = (size_t)r0 * U_ + (sw0 >> 1);                                  \
        al0 = wv * 1024;                                                     \
        int r1 = 32 + r0;                             /* A rows 32..63 */    \
        int sw1 = kb0 ^ ((r1 & 7) << 4);                                     \
        ag1 = (size_t)r1 * U_ + (sw1 >> 1);                                  \
        al1 = 8192 + wv * 1024;                                              \
        wg0 = (size_t)r0 * U_ + (sw0 >> 1);           /* W rows 0..31 */     \
        wl0 = 16384 + wv * 1024;                                             \
    }                                                                        \
    int aoff[4], woff[4];                                                    \
    {                                                                        \
        const int lkb = (l >> 4) << 4;                                       \
        _Pragma("unroll")                                                    \
        for (int ks = 0; ks < 4; ++ks) {                                     \
            int kb = ks * 64 + lkb;                                          \
            int ar = rq * 16 + lr, wr = ch * 16 + lr;                        \
            aoff[ks] = ar * 256 + (kb ^ ((ar & 7) << 4));                    \
            woff[ks] = 16384 + wr * 256 + (kb ^ ((wr & 7) << 4));            \
        }                                                                    \
    }

#define ISSUE(Ap, Wp, tt) do {                                               \
        const int k0_ = (tt) * 128;                                          \
        char* sb_ = stg + ((tt) % 6) * 24576;                                \
        gld16((Ap) + ag0 + k0_, sb_ + al0);                                  \
        gld16((Ap) + ag1 + k0_, sb_ + al1);                                  \
        gld16((Wp) + wg0 + k0_, sb_ + wl0);                                  \
    } while (0)

// per-wave: 3 loads/tile. After issuing through tile tt+4, wait vmcnt(12)
// leaves exactly tiles tt+1..tt+4 outstanding => tile tt landed. Issue of
// tile tt+5 happens AFTER the barrier (it overwrites buffer (tt-1)%6, which
// all waves finished consuming — lgkmcnt before MFMA guarantees reads done).
#define GEMM_LOOP(Ap, Wp)                                                    \
    ISSUE(Ap, Wp, 0); ISSUE(Ap, Wp, 1); ISSUE(Ap, Wp, 2);                    \
    ISSUE(Ap, Wp, 3); ISSUE(Ap, Wp, 4);                                      \
    _Pragma("unroll")                                                        \
    for (int tt = 0; tt < 16; ++tt) {                                        \
        if (tt < 12)       asm volatile("s_waitcnt vmcnt(12)" ::: "memory"); \
        else if (tt == 12) asm volatile("s_waitcnt vmcnt(9)" ::: "memory");  \
        else if (tt == 13) asm volatile("s_waitcnt vmcnt(6)" ::: "memory");  \
        else if (tt == 14) asm volatile("s_waitcnt vmcnt(3)" ::: "memory");  \
        else               asm volatile("s_waitcnt vmcnt(0)" ::: "memory");  \
        __builtin_amdgcn_s_barrier();                                        \
        if (tt + 5 < 16) ISSUE(Ap, Wp, tt + 5);                              \
        const char* sb = stg + (tt % 6) * 24576;                             \
        _Pragma("unroll")                                                    \
        for (int ks = 0; ks < 4; ++ks) {                                     \
            bf16x8 av = *(const bf16x8*)(sb + aoff[ks]);                     \
            bf16x8 wf = *(const bf16x8*)(sb + woff[ks]);                     \
            acc = MFMA(av, wf, acc);                                         \
        }                                                                    \
    }

// store S tile (64 rows x 32 cols of tile `til`) to ZG, nontemporal
#define EPI_ZG(ZG) do {                                                      \
        const int l4_ = (l >> 4) << 2;                                       \
        _Pragma("unroll")                                                    \
        for (int r = 0; r < 4; ++r) {                                        \
            int row = rq * 16 + l4_ + r;                                     \
            int col = til * 32 + ch * 16 + lr;                               \
            __builtin_nontemporal_store(acc[r], &(ZG)[(size_t)row * G4_ + col]); \
        }                                                                    \
    } while (0)

#define EPI_FILL_PLAIN() do {                                                \
        __syncthreads();   /* sg aliases stage buf 2 */                      \
        const int l4_ = (l >> 4) << 2;                                       \
        _Pragma("unroll")                                                    \
        for (int r = 0; r < 4; ++r)                                          \
            sg[rq * 16 + l4_ + r][ch * 16 + lr] = acc[r];                    \
    } while (0)

#define EPI_FILL_ZG(ZGIN) do {                                               \
        __syncthreads();   /* sg aliases stage buf 2 */                      \
        const int l4_ = (l >> 4) << 2;                                       \
        _Pragma("unroll")                                                    \
        for (int r = 0; r < 4; ++r) {                                        \
            int row = rq * 16 + l4_ + r;                                     \
            int col = til * 32 + ch * 16 + lr;                               \
            sg[row][ch * 16 + lr] =                                          \
                acc[r] + __builtin_nontemporal_load(&(ZGIN)[(size_t)row * G4_ + col]); \
        }                                                                    \
    } while (0)

// BASEEXPR may use b, u, gi. 512 threads cover 64 rows x 8 units exactly.
#define EPI_GATE(BASEEXPR, CST, HNEW) do {                                   \
        __syncthreads();                                                     \
        const int b = t >> 3, uu = t & 7;                                    \
        const int u = til * 8 + uu;                                          \
        float g[4];                                                          \
        _Pragma("unroll")                                                    \
        for (int gi = 0; gi < 4; ++gi)                                       \
            g[gi] = sg[b][gi * 8 + uu] + (BASEEXPR);                         \
        float* cp = (CST) + (size_t)b * U_ + u;                              \
        const float c_ = *cp;                                                \
        const float cn = sigf(g[1]) * c_ + sigf(g[0]) * tanhf(g[2]);         \
        const float hn = sigf(g[3]) * tanhf(cn);                             \
        *cp = cn;                                                            \
        (HNEW)[(size_t)b * U_ + u] = f2bf(hn);                               \
    } while (0)

// ---- job bodies (shared between cooperative kernel and fallback kernels) ----
// X jobs: [0,256) KG2(tstep-1) (skipped at tstep==0); [256,512) REC0(tstep);
//         [512,768) REC1(tstep).   Y jobs: [0,256) REC2(tstep); [256,512) KG1(tstep).
#define XJOB(JOB, TSTEP, P) do {                                             \
        if ((JOB) < 256) {                                                   \
            if ((TSTEP) >= 1) {                                              \
                const int til = (JOB);                                       \
                const unsigned short* Aj = h1b[(P)];                         \
                const unsigned short* Wj = k2P + (size_t)til * 32 * U_;      \
                f32x4 acc = {};                                              \
                GEMM_LOOP(Aj, Wj);                                           \
                EPI_FILL_ZG(zg2);                                            \
                EPI_GATE(b2v[gi * 2048 + u], cst2,                           \
                         h2hist + (size_t)(TSTEP) * B_ * U_);                \
            }                                                                \
        } else if ((JOB) < 512) {                                            \
            const int til = (JOB) - 256;                                     \
            const unsigned short* Aj = h0b[(P)];                             \
            const unsigned short* Wj = rk0P + (size_t)til * 32 * U_;         \
            f32x4 acc = {};                                                  \
            GEMM_LOOP(Aj, Wj);                                               \
            EPI_FILL_PLAIN();                                                \
            EPI_GATE(xk0[(size_t)b * G4_ + gi * 2048 + u], cst0,             \
                     h0b[(P) ^ 1]);                                          \
        } else {                                                             \
            const int til = (JOB) - 512;                                     \
            const unsigned short* Aj = h1b[(P)];                             \
            const unsigned short* Wj = rk1P + (size_t)til * 32 * U_;         \
            f32x4 acc = {};                                                  \
            GEMM_LOOP(Aj, Wj);                                               \
            EPI_ZG(zg1);                                                     \
        }                                                                    \
    } while (0)

#define YJOB(JOB, TSTEP, P) do {                                             \
        if ((JOB) < 256) {                                                   \
            const int til = (JOB);                                           \
            const unsigned short* Aj = h2hist + (size_t)(TSTEP) * B_ * U_;   \
            const unsigned short* Wj = rk2P + (size_t)til * 32 * U_;         \
            f32x4 acc = {};                                                  \
            GEMM_LOOP(Aj, Wj);                                               \
            EPI_ZG(zg2);                                                     \
        } else {                                                             \
            const int til = (JOB) - 256;                                     \
            const unsigned short* Aj = h0b[(P) ^ 1];                         \
            const unsigned short* Wj = k1P + (size_t)til * 32 * U_;          \
            f32x4 acc = {};                                                  \
            GEMM_LOOP(Aj, Wj);                                               \
            EPI_FILL_ZG(zg1);                                                \
            EPI_GATE(b1v[gi * 2048 + u], cst1, h1b[(P) ^ 1]);                \
        }                                                                    \
    } while (0)

#define STEP_LOCALS()                                                        \
    __shared__ char stg[6 * 24576];                                          \
    auto sg = reinterpret_cast<float(*)[33]>(stg + 2 * 24576);               \
    const int t = threadIdx.x, wv = t >> 6, l = t & 63;                      \
    const int rq = wv & 3, ch = wv >> 2, lr = l & 15;                        \
    unsigned short* h0b[2] = {h0b0, h0b1};                                   \
    unsigned short* h1b[2] = {h1b0, h1b1};

// ---------------- one-time weight prep ----------------

__global__ __launch_bounds__(256) void transpose_cvt(const float* __restrict__ W,
                                                     unsigned short* __restrict__ Wt,
                                                     int K, int N, int row_off)
{
    __shared__ float tile[32][33];
    const int nb = blockIdx.x * 32, kb = blockIdx.y * 32;
    const int tx = threadIdx.x & 31, ty = threadIdx.x >> 5;   // 32 x 8
    #pragma unroll
    for (int i = 0; i < 4; ++i)
        tile[ty + i * 8][tx] = W[(size_t)(row_off + kb + ty + i * 8) * N + nb + tx];
    __syncthreads();
    #pragma unroll
    for (int i = 0; i < 4; ++i)
        Wt[(size_t)(nb + ty + i * 8) * K + kb + tx] = f2bf(tile[tx][ty + i * 8]);
}

// Packed transpose: original col n = g*2048+u -> packed row (u>>3)*32 + g*8 + (u&7).
__global__ __launch_bounds__(256) void transpose_cvt_packed(const float* __restrict__ W,
                                                            unsigned short* __restrict__ Wt)
{
    __shared__ float tile[32][33];
    const int nb = blockIdx.x * 32, kb = blockIdx.y * 32;   // N=8192, K=2048
    const int tx = threadIdx.x & 31, ty = threadIdx.x >> 5;
    #pragma unroll
    for (int i = 0; i < 4; ++i)
        tile[ty + i * 8][tx] = W[(size_t)(kb + ty + i * 8) * G4_ + nb + tx];
    __syncthreads();
    #pragma unroll
    for (int i = 0; i < 4; ++i) {
        int n = nb + ty + i * 8;
        int g = n >> 11, u = n & 2047;
        int prow = ((u >> 3) << 5) + (g << 3) + (u & 7);
        Wt[(size_t)prow * U_ + kb + tx] = f2bf(tile[tx][ty + i * 8]);
    }
}

// w_outT[d][k] = bf16(w_out[k*90+d]) for d<90, else 0   (96 x 2048)
__global__ __launch_bounds__(256) void wout_cvt(const float* __restrict__ w_out,
                                                unsigned short* __restrict__ w_outT)
{
    int i = blockIdx.x * 256 + threadIdx.x;        // 96*2048
    int d = i >> 11, k = i & 2047;
    w_outT[i] = (d < DIN_) ? f2bf(w_out[(size_t)k * DIN_ + d]) : (unsigned short)0;
}

__global__ __launch_bounds__(256) void cvt_z(const float* __restrict__ z,
                                             unsigned short* __restrict__ zb)
{
    int i = blockIdx.x * 256 + threadIdx.x;        // 64*512
    zb[i] = f2bf(z[i]);
}

// initial h (bf16) and c (fp32) from the setup GEMM output st
__global__ __launch_bounds__(256) void hcinit(const float* __restrict__ st,
                                              unsigned short* __restrict__ h0,
                                              unsigned short* __restrict__ h1,
                                              unsigned short* __restrict__ h2s0,
                                              float* __restrict__ c0,
                                              float* __restrict__ c1,
                                              float* __restrict__ c2)
{
    int idx = blockIdx.x * 256 + threadIdx.x;      // 3*64*2048
    int u = idx & 2047, b = (idx >> 11) & 63, ly = idx >> 17;
    float hv = st[(size_t)b * STLD + ly * 4096 + u];
    float cv = st[(size_t)b * STLD + ly * 4096 + 2048 + u];
    unsigned short* h = (ly == 0) ? h0 : (ly == 1) ? h1 : h2s0;
    float* c = (ly == 0) ? c0 : (ly == 1) ? c1 : c2;
    h[(size_t)b * 2048 + u] = f2bf(hv);
    c[(size_t)b * 2048 + u] = cv;
}

// ---------------- setup GEMMs (K=512): out[64 x N] = A @ Wt^T + bias ----------------
__global__ __launch_bounds__(256) void gemm_plain(const unsigned short* __restrict__ A, int K,
                                                  const unsigned short* __restrict__ Wt,
                                                  const float* __restrict__ bias,
                                                  float* __restrict__ out, int ldo)
{
    const int t = threadIdx.x, wv = t >> 6, l = t & 63;
    const int wm = (wv >> 1) * 32, n0 = blockIdx.x * 64 + (wv & 1) * 32;
    const int lr = l & 15, lk = (l >> 4) * 8;
    f32x4 acc[2][2] = {};
    for (int kt = 0; kt < K; kt += 32) {
        bf16x8 a0 = *(const bf16x8*)(A + (size_t)(wm + lr) * K + kt + lk);
        bf16x8 a1 = *(const bf16x8*)(A + (size_t)(wm + 16 + lr) * K + kt + lk);
        bf16x8 w0 = *(const bf16x8*)(Wt + (size_t)(n0 + lr) * K + kt + lk);
        bf16x8 w1 = *(const bf16x8*)(Wt + (size_t)(n0 + 16 + lr) * K + kt + lk);
        acc[0][0] = MFMA(a0, w0, acc[0][0]);
        acc[0][1] = MFMA(a0, w1, acc[0][1]);
        acc[1][0] = MFMA(a1, w0, acc[1][0]);
        acc[1][1] = MFMA(a1, w1, acc[1][1]);
    }
    #pragma unroll
    for (int mi = 0; mi < 2; ++mi)
        #pragma unroll
        for (int ni = 0; ni < 2; ++ni)
            #pragma unroll
            for (int r = 0; r < 4; ++r) {
                int row = wm + mi * 16 + (l >> 4) * 4 + r;
                int col = n0 + ni * 16 + lr;
                out[(size_t)row * ldo + col] = acc[mi][ni][r] + bias[col];
            }
}

// ---------------- persistent cooperative time loop (grid 256 = 1 block/CU) ----------------
__global__ __launch_bounds__(512, 2) void lstm_loop(
    unsigned short* h0b0, unsigned short* h0b1,
    unsigned short* h1b0, unsigned short* h1b1,
    unsigned short* h2hist,
    const unsigned short* rk0P, const unsigned short* rk1P, const unsigned short* rk2P,
    const unsigned short* k1P, const unsigned short* k2P,
    const float* xk0, const float* b1v, const float* b2v,
    float* zg1, float* zg2,
    float* cst0, float* cst1, float* cst2)
{
    STEP_LOCALS();
    cg::grid_group grid = cg::this_grid();
    const int blk = blockIdx.x;
    GEMM_PROLOG();

    for (int tstep = 0; tstep <= T_; ++tstep) {
        const int p = tstep & 1;
        XJOB(blk, tstep, p);
        if (tstep == T_) break;                  // epilogue: only final KG2
        __syncthreads();                         // stage-buffer reuse fence between jobs
        XJOB(blk + 256, tstep, p);
        __syncthreads();
        XJOB(blk + 512, tstep, p);
        grid.sync();
        YJOB(blk, tstep, p);
        __syncthreads();
        YJOB(blk + 256, tstep, p);
        grid.sync();
    }
}

// ---------------- fallback per-step kernels (same job bodies) ----------------
__global__ __launch_bounds__(512, 2) void fbX(
    unsigned short* h0b0, unsigned short* h0b1,
    unsigned short* h1b0, unsigned short* h1b1,
    unsigned short* h2hist,
    const unsigned short* rk0P, const unsigned short* rk1P, const unsigned short* rk2P,
    const unsigned short* k1P, const unsigned short* k2P,
    const float* xk0, const float* b1v, const float* b2v,
    float* zg1, float* zg2,
    float* cst0, float* cst1, float* cst2, int tstep)
{
    STEP_LOCALS();
    (void)rk2P; (void)k1P; (void)b1v; (void)cst1;
    GEMM_PROLOG();
    const int p = tstep & 1;
    const int job = blockIdx.y * 256 + blockIdx.x;
    XJOB(job, tstep, p);
}

__global__ __launch_bounds__(512, 2) void fbY(
    unsigned short* h0b0, unsigned short* h0b1,
    unsigned short* h1b0, unsigned short* h1b1,
    unsigned short* h2hist,
    const unsigned short* rk0P, const unsigned short* rk1P, const unsigned short* rk2P,
    const unsigned short* k1P, const unsigned short* k2P,
    const float* xk0, const float* b1v, const float* b2v,
    float* zg1, float* zg2,
    float* cst0, float* cst1, float* cst2, int tstep)
{
    STEP_LOCALS();
    (void)rk0P; (void)k2P; (void)b2v; (void)cst0; (void)cst2; (void)xk0;
    GEMM_PROLOG();
    const int p = tstep & 1;
    const int job = blockIdx.y * 256 + blockIdx.x;
    YJOB(job, tstep, p);
}

// ---------------- batched output projection: ONE GEMM after the time loop ----------------
__global__ __launch_bounds__(256) void outproj_all(const unsigned short* __restrict__ h2h,
                                                   const unsigned short* __restrict__ w_outT,
                                                   const float* __restrict__ b_out,
                                                   float* __restrict__ out)
{
    const int t = threadIdx.x, wv = t >> 6, l = t & 63;
    const int m0 = blockIdx.x * 64 + wv * 16;
    const int lr = l & 15, lk = (l >> 4) * 8;
    const unsigned short* ap = h2h + (size_t)(m0 + lr) * U_ + lk;
    f32x4 acc[6] = {};
    for (int kt = 0; kt < U_; kt += 32) {
        bf16x8 af = *(const bf16x8*)(ap + kt);
        #pragma unroll
        for (int n = 0; n < 6; ++n) {
            bf16x8 wf = *(const bf16x8*)(w_outT + (size_t)(n * 16 + lr) * U_ + kt + lk);
            acc[n] = MFMA(af, wf, acc[n]);
        }
    }
    const int l4 = (l >> 4) * 4;
    #pragma unroll
    for (int n = 0; n < 6; ++n) {
        const int col = n * 16 + lr;
        if (col < DIN_) {
            #pragma unroll
            for (int r = 0; r < 4; ++r) {
                int row = m0 + l4 + r;                  // = tstep*64 + b
                int tt = row >> 6, b = row & 63;
                out[((size_t)b * T_ + tt) * DIN_ + col] = acc[n][r] + b_out[col];
            }
        }
    }
}

extern "C" void kernel_launch(void* const* d_in, const int* in_sizes, int n_in,
                              void* d_out, int out_size, void* d_ws, size_t ws_size,
                              hipStream_t stream)
{
    const float* z      = (const float*)d_in[0];
    const float* w_init = (const float*)d_in[1];
    const float* b_init = (const float*)d_in[2];
    const float* k0     = (const float*)d_in[3];
    const float* rk0    = (const float*)d_in[4];
    const float* b0     = (const float*)d_in[5];
    const float* k1     = (const float*)d_in[6];
    const float* rk1    = (const float*)d_in[7];
    const float* b1     = (const float*)d_in[8];
    const float* k2     = (const float*)d_in[9];
    const float* rk2    = (const float*)d_in[10];
    const float* b2     = (const float*)d_in[11];
    const float* w_out  = (const float*)d_in[12];
    const float* b_out  = (const float*)d_in[13];
    float* out = (float*)d_out;
    (void)in_sizes; (void)n_in; (void)out_size; (void)ws_size;

    // workspace carve-up (256B aligned), total ~210 MB
    size_t off = 0;
    char* base = (char*)d_ws;
    auto alloc = [&](size_t bytes) { void* p = base + off; off += (bytes + 255) & ~(size_t)255; return p; };
    unsigned short* rk0P = (unsigned short*)alloc((size_t)U_ * G4_ * 2);
    unsigned short* rk1P = (unsigned short*)alloc((size_t)U_ * G4_ * 2);
    unsigned short* rk2P = (unsigned short*)alloc((size_t)U_ * G4_ * 2);
    unsigned short* k1P  = (unsigned short*)alloc((size_t)U_ * G4_ * 2);
    unsigned short* k2P  = (unsigned short*)alloc((size_t)U_ * G4_ * 2);
    unsigned short* wiT  = (unsigned short*)alloc((size_t)STLD * Z_ * 2);
    unsigned short* k0T  = (unsigned short*)alloc((size_t)G4_ * Z_ * 2);
    unsigned short* woT  = (unsigned short*)alloc((size_t)96 * U_ * 2);
    unsigned short* zb   = (unsigned short*)alloc((size_t)B_ * Z_ * 2);
    unsigned short* hb0[2], *hb1[2];
    for (int p = 0; p < 2; ++p) hb0[p] = (unsigned short*)alloc((size_t)B_ * U_ * 2);
    for (int p = 0; p < 2; ++p) hb1[p] = (unsigned short*)alloc((size_t)B_ * U_ * 2);
    unsigned short* h2hist = (unsigned short*)alloc((size_t)(T_ + 1) * B_ * U_ * 2);
    float* st   = (float*)alloc((size_t)B_ * STLD * 4);
    float* xk0  = (float*)alloc((size_t)B_ * G4_ * 4);
    float* zg1  = (float*)alloc((size_t)B_ * G4_ * 4);
    float* zg2  = (float*)alloc((size_t)B_ * G4_ * 4);
    float* cst0 = (float*)alloc((size_t)B_ * U_ * 4);
    float* cst1 = (float*)alloc((size_t)B_ * U_ * 4);
    float* cst2 = (float*)alloc((size_t)B_ * U_ * 4);

    // --- one-time conversions ---
    transpose_cvt_packed<<<dim3(G4_ / 32, U_ / 32), 256, 0, stream>>>(rk0, rk0P);
    transpose_cvt_packed<<<dim3(G4_ / 32, U_ / 32), 256, 0, stream>>>(rk1, rk1P);
    transpose_cvt_packed<<<dim3(G4_ / 32, U_ / 32), 256, 0, stream>>>(rk2, rk2P);
    transpose_cvt_packed<<<dim3(G4_ / 32, U_ / 32), 256, 0, stream>>>(k1, k1P);
    transpose_cvt_packed<<<dim3(G4_ / 32, U_ / 32), 256, 0, stream>>>(k2, k2P);
    transpose_cvt<<<dim3(STLD / 32, Z_ / 32), 256, 0, stream>>>(w_init, wiT, Z_, STLD, 0);
    transpose_cvt<<<dim3(G4_ / 32, Z_ / 32), 256, 0, stream>>>(k0, k0T, Z_, G4_, DIN_);
    wout_cvt<<<dim3(96 * U_ / 256), 256, 0, stream>>>(w_out, woT);
    cvt_z<<<dim3(B_ * Z_ / 256), 256, 0, stream>>>(z, zb);

    // --- setup: st = zb @ wiT^T + b_init ; xk0 = zb @ k0T^T + b0 ---
    gemm_plain<<<dim3(STLD / 64), 256, 0, stream>>>(zb, Z_, wiT, b_init, st, STLD);
    gemm_plain<<<dim3(G4_ / 64), 256, 0, stream>>>(zb, Z_, k0T, b0, xk0, G4_);
    hcinit<<<dim3(3 * B_ * U_ / 256), 256, 0, stream>>>(st, hb0[0], hb1[0], h2hist,
                                                        cst0, cst1, cst2);

    // --- whole time loop: ONE cooperative launch (256 blocks = 1/CU) ---
    void* kargs[] = {
        &hb0[0], &hb0[1], &hb1[0], &hb1[1], &h2hist,
        &rk0P, &rk1P, &rk2P, &k1P, &k2P,
        (void*)&xk0, (void*)&b1, (void*)&b2,
        &zg1, &zg2, &cst0, &cst1, &cst2,
    };
    hipError_t cerr = hipLaunchCooperativeKernel((const void*)lstm_loop, dim3(256),
                                                 dim3(512), kargs, 0, stream);
    if (cerr != hipSuccess) {
        // fallback: per-step launches (same job bodies)
        for (int tstep = 0; tstep < T_; ++tstep) {
            fbX<<<dim3(256, 3), 512, 0, stream>>>(hb0[0], hb0[1], hb1[0], hb1[1], h2hist,
                                                  rk0P, rk1P, rk2P, k1P, k2P,
                                                  xk0, b1, b2, zg1, zg2,
                                                  cst0, cst1, cst2, tstep);
            fbY<<<dim3(256, 2), 512, 0, stream>>>(hb0[0], hb0[1], hb1[0], hb1[1], h2hist,
                                                  rk0P, rk1P, rk2P, k1P, k2P,
                                                  xk0, b1, b2, zg1, zg2,
                                                  cst0, cst1, cst2, tstep);
        }
        fbX<<<dim3(256, 1), 512, 0, stream>>>(hb0[0], hb0[1], hb1[0], hb1[1], h2hist,
                                              rk0P, rk1P, rk2P, k1P, k2P,
                                              xk0, b1, b2, zg1, zg2,
                                              cst0, cst1, cst2, T_);
    }
    // --- all 32 output projections in one GEMM ---
    outproj_all<<<dim3(T_ * B_ / 64), 256, 0, stream>>>(h2hist + (size_t)B_ * U_, woT, b_out, out);
}

// Round 18
// 1484.035 us; speedup vs baseline: 2.8655x; 2.8655x over previous
//
#include <hip/hip_runtime.h>
#include <cstdint>

// Problem constants
#define B_   64
#define Z_   512
#define U_   2048
#define T_   32
#define DIN_ 90
#define G4_  8192      // 4*U
#define STLD 12288     // setup GEMM output row stride: h at +l*4096, c at +l*4096+2048

using bf16x8 = __attribute__((ext_vector_type(8))) short;   // 8 bf16 = 4 VGPRs
using f32x4  = __attribute__((ext_vector_type(4))) float;

#define MFMA(a, b, c) __builtin_amdgcn_mfma_f32_16x16x32_bf16((a), (b), (c), 0, 0, 0)

__device__ __forceinline__ unsigned short f2bf(float f) {
    unsigned int u = __float_as_uint(f);
    unsigned int r = (u + 0x7FFFu + ((u >> 16) & 1u)) >> 16;   // RNE
    return (unsigned short)r;
}
__device__ __forceinline__ float sigf(float x) { return 1.f / (1.f + expf(-x)); }

// async global->LDS, 16 B per lane; LDS dest is wave-uniform base + lane*16
__device__ __forceinline__ void gld16(const void* g, void* l) {
    __builtin_amdgcn_global_load_lds(
        (const __attribute__((address_space(1))) unsigned int*)g,
        (__attribute__((address_space(3))) unsigned int*)l, 16, 0, 0);
}

// ======== staged K=2048 GEMM core as macros (LDS at kernel scope; passing ========
// ======== __shared__ pointers through fn params ICEs clang — r11 lesson)  ========
// 512 threads = 8 waves. Block tile: 64 rows x 32 packed cols (W panel read ONCE
// per launch — r13's y-split read it twice). Wave (rq=wv&3, ch=wv>>2) does 16x16.
// KT=128; stage = A 16KB | W 8KB = 24KB; 3 stages = 72KB; counted vmcnt(3).
// T2 XOR swizzle via pre-swizzled global source. sg aliases stage buffer 2
// (last tile reads buffer 0; defensive barrier before fill).
// NOTE (r15-r17 post-mortem): persistent-cooperative variants of this loop
// (1 block/CU, grid.sync) ran 2.7x SLOWER — multi-launch with 2-3 blocks/CU
// wins because inter-block overlap hides per-tile stalls. Keep this schedule.
// Requires in scope: stg, t, wv, l, prow0, rq, ch, lr.
#define GEMM_PROLOG()                                                        \
    size_t ag0, ag1, wg0; unsigned al0, al1, wl0;                            \
    {                                                                        \
        int kb0 = (l & 15) << 4;                                             \
        int r0 = wv * 4 + (l >> 4);                   /* A rows 0..31 */     \
        int sw0 = kb0 ^ ((r0 & 7) << 4);                                     \
        ag0 = (size_t)r0 * U_ + (sw0 >> 1);                                  \
        al0 = wv * 1024;                                                     \
        int r1 = 32 + r0;                             /* A rows 32..63 */    \
        int sw1 = kb0 ^ ((r1 & 7) << 4);                                     \
        ag1 = (size_t)r1 * U_ + (sw1 >> 1);                                  \
        al1 = 8192 + wv * 1024;                                              \
        int rw = r0;                                  /* W rows 0..31 */     \
        int sww = kb0 ^ ((rw & 7) << 4);                                     \
        wg0 = (size_t)(prow0 + rw) * U_ + (sww >> 1);                        \
        wl0 = 16384 + wv * 1024;                                             \
    }                                                                        \
    int aoff[4], woff[4];                                                    \
    {                                                                        \
        const int lkb = (l >> 4) << 4;                                       \
        _Pragma("unroll")                                                    \
        for (int ks = 0; ks < 4; ++ks) {                                     \
            int kb = ks * 64 + lkb;                                          \
            int ar = rq * 16 + lr, wr = ch * 16 + lr;                        \
            aoff[ks] = ar * 256 + (kb ^ ((ar & 7) << 4));                    \
            woff[ks] = 16384 + wr * 256 + (kb ^ ((wr & 7) << 4));            \
        }                                                                    \
    }

#define ISSUE(Ap, Wp, tt) do {                                               \
        const int k0_ = (tt) * 128;                                          \
        char* sb_ = stg + ((tt) % 3) * 24576;                                \
        gld16((Ap) + ag0 + k0_, sb_ + al0);                                  \
        gld16((Ap) + ag1 + k0_, sb_ + al1);                                  \
        gld16((Wp) + wg0 + k0_, sb_ + wl0);                                  \
    } while (0)

#define GEMM_LOOP(Ap, Wp)                                                    \
    ISSUE(Ap, Wp, 0);                                                        \
    ISSUE(Ap, Wp, 1);                                                        \
    for (int tt = 0; tt < 16; ++tt) {                                        \
        if (tt < 15) asm volatile("s_waitcnt vmcnt(3)" ::: "memory");        \
        else         asm volatile("s_waitcnt vmcnt(0)" ::: "memory");        \
        __builtin_amdgcn_s_barrier();                                        \
        if (tt + 2 < 16) ISSUE(Ap, Wp, tt + 2);                              \
        const char* sb = stg + (tt % 3) * 24576;                             \
        _Pragma("unroll")                                                    \
        for (int ks = 0; ks < 4; ++ks) {                                     \
            bf16x8 av = *(const bf16x8*)(sb + aoff[ks]);                     \
            bf16x8 wf = *(const bf16x8*)(sb + woff[ks]);                     \
            acc = MFMA(av, wf, acc);                                         \
        }                                                                    \
    }

// mode-1 epilogue: nontemporal store S tile (64 rows x 32 cols) to ZG
#define EPI_ZG(ZG) do {                                                      \
        const int l4_ = (l >> 4) << 2;                                       \
        _Pragma("unroll")                                                    \
        for (int r = 0; r < 4; ++r) {                                        \
            int row = rq * 16 + l4_ + r;                                     \
            int col = prow0 + ch * 16 + lr;                                  \
            __builtin_nontemporal_store(acc[r], &(ZG)[(size_t)row * G4_ + col]); \
        }                                                                    \
    } while (0)

// gate epilogues: fill sg (plain or +zg), then LSTM cell for 64 rows x 8 units
#define EPI_FILL_PLAIN() do {                                                \
        __syncthreads();   /* sg aliases stage buf 2 */                      \
        const int l4_ = (l >> 4) << 2;                                       \
        _Pragma("unroll")                                                    \
        for (int r = 0; r < 4; ++r)                                          \
            sg[rq * 16 + l4_ + r][ch * 16 + lr] = acc[r];                    \
    } while (0)

#define EPI_FILL_ZG(ZGIN) do {                                               \
        __syncthreads();   /* sg aliases stage buf 2 */                      \
        const int l4_ = (l >> 4) << 2;                                       \
        _Pragma("unroll")                                                    \
        for (int r = 0; r < 4; ++r) {                                        \
            int row = rq * 16 + l4_ + r;                                     \
            int col = prow0 + ch * 16 + lr;                                  \
            sg[row][ch * 16 + lr] =                                          \
                acc[r] + __builtin_nontemporal_load(&(ZGIN)[(size_t)row * G4_ + col]); \
        }                                                                    \
    } while (0)

// BASEEXPR may use b, u, gi. 512 threads cover 64 rows x 8 units exactly.
#define EPI_GATE(BASEEXPR, CST, HNEW) do {                                   \
        __syncthreads();                                                     \
        const int b = t >> 3, uu = t & 7;                                    \
        const int u = blockIdx.x * 8 + uu;                                   \
        float g[4];                                                          \
        _Pragma("unroll")                                                    \
        for (int gi = 0; gi < 4; ++gi)                                       \
            g[gi] = sg[b][gi * 8 + uu] + (BASEEXPR);                         \
        float* cp = (CST) + (size_t)b * U_ + u;                              \
        const float c_ = *cp;                                                \
        const float cn = sigf(g[1]) * c_ + sigf(g[0]) * tanhf(g[2]);         \
        const float hn = sigf(g[3]) * tanhf(cn);                             \
        *cp = cn;                                                            \
        (HNEW)[(size_t)b * U_ + u] = f2bf(hn);                               \
    } while (0)

#define STEP_COMMON()                                                        \
    __shared__ char stg[3 * 24576];                                          \
    auto sg = reinterpret_cast<float(*)[33]>(stg + 2 * 24576);               \
    const int t = threadIdx.x, wv = t >> 6, l = t & 63;                      \
    const int prow0 = blockIdx.x * 32;                                       \
    const int rq = wv & 3, ch = wv >> 2, lr = l & 15;

// ---------------- one-time weight prep ----------------

__global__ __launch_bounds__(256) void transpose_cvt(const float* __restrict__ W,
                                                     unsigned short* __restrict__ Wt,
                                                     int K, int N, int row_off)
{
    __shared__ float tile[32][33];
    const int nb = blockIdx.x * 32, kb = blockIdx.y * 32;
    const int tx = threadIdx.x & 31, ty = threadIdx.x >> 5;   // 32 x 8
    #pragma unroll
    for (int i = 0; i < 4; ++i)
        tile[ty + i * 8][tx] = W[(size_t)(row_off + kb + ty + i * 8) * N + nb + tx];
    __syncthreads();
    #pragma unroll
    for (int i = 0; i < 4; ++i)
        Wt[(size_t)(nb + ty + i * 8) * K + kb + tx] = f2bf(tile[tx][ty + i * 8]);
}

// Packed transpose: original col n = g*2048+u -> packed row (u>>3)*32 + g*8 + (u&7).
__global__ __launch_bounds__(256) void transpose_cvt_packed(const float* __restrict__ W,
                                                            unsigned short* __restrict__ Wt)
{
    __shared__ float tile[32][33];
    const int nb = blockIdx.x * 32, kb = blockIdx.y * 32;   // N=8192, K=2048
    const int tx = threadIdx.x & 31, ty = threadIdx.x >> 5;
    #pragma unroll
    for (int i = 0; i < 4; ++i)
        tile[ty + i * 8][tx] = W[(size_t)(kb + ty + i * 8) * G4_ + nb + tx];
    __syncthreads();
    #pragma unroll
    for (int i = 0; i < 4; ++i) {
        int n = nb + ty + i * 8;
        int g = n >> 11, u = n & 2047;
        int prow = ((u >> 3) << 5) + (g << 3) + (u & 7);
        Wt[(size_t)prow * U_ + kb + tx] = f2bf(tile[tx][ty + i * 8]);
    }
}

// w_outT[d][k] = bf16(w_out[k*90+d]) for d<90, else 0   (96 x 2048)
__global__ __launch_bounds__(256) void wout_cvt(const float* __restrict__ w_out,
                                                unsigned short* __restrict__ w_outT)
{
    int i = blockIdx.x * 256 + threadIdx.x;        // 96*2048
    int d = i >> 11, k = i & 2047;
    w_outT[i] = (d < DIN_) ? f2bf(w_out[(size_t)k * DIN_ + d]) : (unsigned short)0;
}

__global__ __launch_bounds__(256) void cvt_z(const float* __restrict__ z,
                                             unsigned short* __restrict__ zb)
{
    int i = blockIdx.x * 256 + threadIdx.x;        // 64*512
    zb[i] = f2bf(z[i]);
}

// initial h (bf16) and c (fp32) from the setup GEMM output st
__global__ __launch_bounds__(256) void hcinit(const float* __restrict__ st,
                                              unsigned short* __restrict__ h0,
                                              unsigned short* __restrict__ h1,
                                              unsigned short* __restrict__ h2s0,
                                              float* __restrict__ c0,
                                              float* __restrict__ c1,
                                              float* __restrict__ c2)
{
    int idx = blockIdx.x * 256 + threadIdx.x;      // 3*64*2048
    int u = idx & 2047, b = (idx >> 11) & 63, ly = idx >> 17;
    float hv = st[(size_t)b * STLD + ly * 4096 + u];
    float cv = st[(size_t)b * STLD + ly * 4096 + 2048 + u];
    unsigned short* h = (ly == 0) ? h0 : (ly == 1) ? h1 : h2s0;
    float* c = (ly == 0) ? c0 : (ly == 1) ? c1 : c2;
    h[(size_t)b * 2048 + u] = f2bf(hv);
    c[(size_t)b * 2048 + u] = cv;
}

// ---------------- setup GEMMs (K=512): out[64 x N] = A @ Wt^T + bias ----------------
__global__ __launch_bounds__(256) void gemm_plain(const unsigned short* __restrict__ A, int K,
                                                  const unsigned short* __restrict__ Wt,
                                                  const float* __restrict__ bias,
                                                  float* __restrict__ out, int ldo)
{
    const int t = threadIdx.x, wv = t >> 6, l = t & 63;
    const int wm = (wv >> 1) * 32, n0 = blockIdx.x * 64 + (wv & 1) * 32;
    const int lr = l & 15, lk = (l >> 4) * 8;
    f32x4 acc[2][2] = {};
    for (int kt = 0; kt < K; kt += 32) {
        bf16x8 a0 = *(const bf16x8*)(A + (size_t)(wm + lr) * K + kt + lk);
        bf16x8 a1 = *(const bf16x8*)(A + (size_t)(wm + 16 + lr) * K + kt + lk);
        bf16x8 w0 = *(const bf16x8*)(Wt + (size_t)(n0 + lr) * K + kt + lk);
        bf16x8 w1 = *(const bf16x8*)(Wt + (size_t)(n0 + 16 + lr) * K + kt + lk);
        acc[0][0] = MFMA(a0, w0, acc[0][0]);
        acc[0][1] = MFMA(a0, w1, acc[0][1]);
        acc[1][0] = MFMA(a1, w0, acc[1][0]);
        acc[1][1] = MFMA(a1, w1, acc[1][1]);
    }
    #pragma unroll
    for (int mi = 0; mi < 2; ++mi)
        #pragma unroll
        for (int ni = 0; ni < 2; ++ni)
            #pragma unroll
            for (int r = 0; r < 4; ++r) {
                int row = wm + mi * 16 + (l >> 4) * 4 + r;
                int col = n0 + ni * 16 + lr;
                out[(size_t)row * ldo + col] = acc[mi][ni][r] + bias[col];
            }
}

// ---------------- pipelined step kernels (512 threads, 64-row blocks) ----------------
// X0 (t=0 prologue): z=0 -> rec0(0); z=1 -> rec1(0)
__global__ __launch_bounds__(512) void stepX0(
    const unsigned short* __restrict__ h0old, const unsigned short* __restrict__ rk0P,
    const float* __restrict__ xk0, float* __restrict__ cst0,
    unsigned short* __restrict__ h0new,
    const unsigned short* __restrict__ h1old, const unsigned short* __restrict__ rk1P,
    float* __restrict__ zg1)
{
    STEP_COMMON();
    const int z = blockIdx.y;
    const unsigned short* A = (z == 0) ? h0old : h1old;
    const unsigned short* W = (z == 0) ? rk0P : rk1P;

    GEMM_PROLOG();
    f32x4 acc = {};
    GEMM_LOOP(A, W);

    if (z == 0) {
        EPI_FILL_PLAIN();
        EPI_GATE(xk0[(size_t)b * G4_ + gi * 2048 + u], cst0, h0new);
    } else {
        EPI_ZG(zg1);
    }
}

// X (t>=1): z=0 -> kgate2(t-1); z=1 -> rec0(t); z=2 -> rec1(t)
__global__ __launch_bounds__(512) void stepX(
    const unsigned short* __restrict__ h1prev, const unsigned short* __restrict__ k2P,
    const float* __restrict__ zg2in, const float* __restrict__ b2v,
    float* __restrict__ cst2, unsigned short* __restrict__ h2out,
    const unsigned short* __restrict__ h0old, const unsigned short* __restrict__ rk0P,
    const float* __restrict__ xk0, float* __restrict__ cst0,
    unsigned short* __restrict__ h0new,
    const unsigned short* __restrict__ h1old, const unsigned short* __restrict__ rk1P,
    float* __restrict__ zg1out)
{
    STEP_COMMON();
    const int z = blockIdx.y;
    const unsigned short* A = (z == 0) ? h1prev : (z == 1) ? h0old : h1old;
    const unsigned short* W = (z == 0) ? k2P : (z == 1) ? rk0P : rk1P;

    GEMM_PROLOG();
    f32x4 acc = {};
    GEMM_LOOP(A, W);

    if (z == 0) {
        EPI_FILL_ZG(zg2in);
        EPI_GATE(b2v[gi * 2048 + u], cst2, h2out);
    } else if (z == 1) {
        EPI_FILL_PLAIN();
        EPI_GATE(xk0[(size_t)b * G4_ + gi * 2048 + u], cst0, h0new);
    } else {
        EPI_ZG(zg1out);
    }
}

// Y: z=0 -> rec2(t); z=1 -> kgate1(t)
__global__ __launch_bounds__(512) void stepY(
    const unsigned short* __restrict__ h2cur, const unsigned short* __restrict__ rk2P,
    float* __restrict__ zg2out,
    const unsigned short* __restrict__ h0new, const unsigned short* __restrict__ k1P,
    const float* __restrict__ zg1in, const float* __restrict__ b1v,
    float* __restrict__ cst1, unsigned short* __restrict__ h1new)
{
    STEP_COMMON();
    const int z = blockIdx.y;
    const unsigned short* A = (z == 0) ? h2cur : h0new;
    const unsigned short* W = (z == 0) ? rk2P : k1P;

    GEMM_PROLOG();
    f32x4 acc = {};
    GEMM_LOOP(A, W);

    if (z == 0) {
        EPI_ZG(zg2out);
    } else {
        EPI_FILL_ZG(zg1in);
        EPI_GATE(b1v[gi * 2048 + u], cst1, h1new);
    }
}

// standalone kgate (epilogue: lone kgate2(31))
__global__ __launch_bounds__(512) void kgate(
    const unsigned short* __restrict__ xNew, const unsigned short* __restrict__ kP,
    const float* __restrict__ zgin, const float* __restrict__ bias,
    float* __restrict__ cst, unsigned short* __restrict__ hNew)
{
    STEP_COMMON();
    GEMM_PROLOG();
    f32x4 acc = {};
    GEMM_LOOP(xNew, kP);

    EPI_FILL_ZG(zgin);
    EPI_GATE(bias[gi * 2048 + u], cst, hNew);
}

// ---------------- batched output projection: ONE GEMM after the time loop ----------------
__global__ __launch_bounds__(256) void outproj_all(const unsigned short* __restrict__ h2h,
                                                   const unsigned short* __restrict__ w_outT,
                                                   const float* __restrict__ b_out,
                                                   float* __restrict__ out)
{
    const int t = threadIdx.x, wv = t >> 6, l = t & 63;
    const int m0 = blockIdx.x * 64 + wv * 16;
    const int lr = l & 15, lk = (l >> 4) * 8;
    const unsigned short* ap = h2h + (size_t)(m0 + lr) * U_ + lk;
    f32x4 acc[6] = {};
    for (int kt = 0; kt < U_; kt += 32) {
        bf16x8 af = *(const bf16x8*)(ap + kt);
        #pragma unroll
        for (int n = 0; n < 6; ++n) {
            bf16x8 wf = *(const bf16x8*)(w_outT + (size_t)(n * 16 + lr) * U_ + kt + lk);
            acc[n] = MFMA(af, wf, acc[n]);
        }
    }
    const int l4 = (l >> 4) * 4;
    #pragma unroll
    for (int n = 0; n < 6; ++n) {
        const int col = n * 16 + lr;
        if (col < DIN_) {
            #pragma unroll
            for (int r = 0; r < 4; ++r) {
                int row = m0 + l4 + r;                  // = tstep*64 + b
                int tt = row >> 6, b = row & 63;
                out[((size_t)b * T_ + tt) * DIN_ + col] = acc[n][r] + b_out[col];
            }
        }
    }
}

extern "C" void kernel_launch(void* const* d_in, const int* in_sizes, int n_in,
                              void* d_out, int out_size, void* d_ws, size_t ws_size,
                              hipStream_t stream)
{
    const float* z      = (const float*)d_in[0];
    const float* w_init = (const float*)d_in[1];
    const float* b_init = (const float*)d_in[2];
    const float* k0     = (const float*)d_in[3];
    const float* rk0    = (const float*)d_in[4];
    const float* b0     = (const float*)d_in[5];
    const float* k1     = (const float*)d_in[6];
    const float* rk1    = (const float*)d_in[7];
    const float* b1     = (const float*)d_in[8];
    const float* k2     = (const float*)d_in[9];
    const float* rk2    = (const float*)d_in[10];
    const float* b2     = (const float*)d_in[11];
    const float* w_out  = (const float*)d_in[12];
    const float* b_out  = (const float*)d_in[13];
    float* out = (float*)d_out;
    (void)in_sizes; (void)n_in; (void)out_size; (void)ws_size;

    // workspace carve-up (256B aligned), total ~210 MB
    size_t off = 0;
    char* base = (char*)d_ws;
    auto alloc = [&](size_t bytes) { void* p = base + off; off += (bytes + 255) & ~(size_t)255; return p; };
    unsigned short* rk0P = (unsigned short*)alloc((size_t)U_ * G4_ * 2);
    unsigned short* rk1P = (unsigned short*)alloc((size_t)U_ * G4_ * 2);
    unsigned short* rk2P = (unsigned short*)alloc((size_t)U_ * G4_ * 2);
    unsigned short* k1P  = (unsigned short*)alloc((size_t)U_ * G4_ * 2);
    unsigned short* k2P  = (unsigned short*)alloc((size_t)U_ * G4_ * 2);
    unsigned short* wiT  = (unsigned short*)alloc((size_t)STLD * Z_ * 2);
    unsigned short* k0T  = (unsigned short*)alloc((size_t)G4_ * Z_ * 2);
    unsigned short* woT  = (unsigned short*)alloc((size_t)96 * U_ * 2);
    unsigned short* zb   = (unsigned short*)alloc((size_t)B_ * Z_ * 2);
    unsigned short* hb0[2], *hb1[2];
    for (int p = 0; p < 2; ++p) hb0[p] = (unsigned short*)alloc((size_t)B_ * U_ * 2);
    for (int p = 0; p < 2; ++p) hb1[p] = (unsigned short*)alloc((size_t)B_ * U_ * 2);
    unsigned short* h2hist = (unsigned short*)alloc((size_t)(T_ + 1) * B_ * U_ * 2);
    float* st   = (float*)alloc((size_t)B_ * STLD * 4);
    float* xk0  = (float*)alloc((size_t)B_ * G4_ * 4);
    float* zg1  = (float*)alloc((size_t)B_ * G4_ * 4);
    float* zg2  = (float*)alloc((size_t)B_ * G4_ * 4);
    float* cst0 = (float*)alloc((size_t)B_ * U_ * 4);
    float* cst1 = (float*)alloc((size_t)B_ * U_ * 4);
    float* cst2 = (float*)alloc((size_t)B_ * U_ * 4);

    // --- one-time conversions ---
    transpose_cvt_packed<<<dim3(G4_ / 32, U_ / 32), 256, 0, stream>>>(rk0, rk0P);
    transpose_cvt_packed<<<dim3(G4_ / 32, U_ / 32), 256, 0, stream>>>(rk1, rk1P);
    transpose_cvt_packed<<<dim3(G4_ / 32, U_ / 32), 256, 0, stream>>>(rk2, rk2P);
    transpose_cvt_packed<<<dim3(G4_ / 32, U_ / 32), 256, 0, stream>>>(k1, k1P);
    transpose_cvt_packed<<<dim3(G4_ / 32, U_ / 32), 256, 0, stream>>>(k2, k2P);
    transpose_cvt<<<dim3(STLD / 32, Z_ / 32), 256, 0, stream>>>(w_init, wiT, Z_, STLD, 0);
    transpose_cvt<<<dim3(G4_ / 32, Z_ / 32), 256, 0, stream>>>(k0, k0T, Z_, G4_, DIN_);
    wout_cvt<<<dim3(96 * U_ / 256), 256, 0, stream>>>(w_out, woT);
    cvt_z<<<dim3(B_ * Z_ / 256), 256, 0, stream>>>(z, zb);

    // --- setup: st = zb @ wiT^T + b_init ; xk0 = zb @ k0T^T + b0 ---
    gemm_plain<<<dim3(STLD / 64), 256, 0, stream>>>(zb, Z_, wiT, b_init, st, STLD);
    gemm_plain<<<dim3(G4_ / 64), 256, 0, stream>>>(zb, Z_, k0T, b0, xk0, G4_);
    hcinit<<<dim3(3 * B_ * U_ / 256), 256, 0, stream>>>(st, hb0[0], hb1[0], h2hist,
                                                        cst0, cst1, cst2);

    // --- pipelined time loop: 2 launches/step; each W panel fetched once ---
    stepX0<<<dim3(U_ / 8, 2), 512, 0, stream>>>(hb0[0], rk0P, xk0, cst0, hb0[1],
                                                hb1[0], rk1P, zg1);
    stepY<<<dim3(U_ / 8, 2), 512, 0, stream>>>(h2hist, rk2P, zg2,
                                               hb0[1], k1P, zg1, b1, cst1, hb1[1]);
    for (int tstep = 1; tstep < T_; ++tstep) {
        const int p = tstep & 1;
        stepX<<<dim3(U_ / 8, 3), 512, 0, stream>>>(
            hb1[p], k2P, zg2, b2, cst2, h2hist + (size_t)tstep * B_ * U_,
            hb0[p], rk0P, xk0, cst0, hb0[p ^ 1],
            hb1[p], rk1P, zg1);
        stepY<<<dim3(U_ / 8, 2), 512, 0, stream>>>(
            h2hist + (size_t)tstep * B_ * U_, rk2P, zg2,
            hb0[p ^ 1], k1P, zg1, b1, cst1, hb1[p ^ 1]);
    }
    // epilogue: lone kgate2(31): h1_new(31)=hb1[0]
    kgate<<<dim3(U_ / 8), 512, 0, stream>>>(hb1[0], k2P, zg2, b2, cst2,
                                            h2hist + (size_t)T_ * B_ * U_);
    // --- all 32 output projections in one GEMM ---
    outproj_all<<<dim3(T_ * B_ / 64), 256, 0, stream>>>(h2hist + (size_t)B_ * U_, woT, b_out, out);
}